// Round 4
// baseline (177.278 us; speedup 1.0000x reference)
//
#include <hip/hip_runtime.h>

#define TT 1024
#define SS 128
#define FF 8
#define CC 256
#define BH 8

// One dispatch, 8192 two-wave workgroups = 16384 independent wave-tasks.
// Wave task (s, ce, b): segment s, 64B channel-slice ce (16 floats of CC=256).
// Exclusive writer per slice -> no atomics, no zero pass, no barriers, no LDS.
// 16384 tasks >> CU residency -> hardware queue-drain does dynamic load
// balancing of the variable segment lengths (d in [0,16)).
__global__ __launch_bounds__(128) void fused_kernel(const float* __restrict__ e,
                                                    const int* __restrict__ dsrc,
                                                    float* __restrict__ out) {
    int tid  = threadIdx.x;
    int lane = tid & 63;
    int w    = tid >> 6;
    int b    = blockIdx.y;
    int task = blockIdx.x * 2 + w;   // [0, 2048): s*16 + ce
    int s    = task >> 4;
    int ce   = task & 15;

    // ---- wave-redundant inclusive scan of d[b, :] (128 ints, 2 per lane) ----
    int2 dd = ((const int2*)(dsrc + b * SS))[lane];
    int incl = dd.x + dd.y;
    #pragma unroll
    for (int off = 1; off < 64; off <<= 1) {
        int n = __shfl_up(incl, off, 64);
        if (lane >= off) incl += n;
    }
    // cum[2l] = incl(l) - dd.y(l); cum[2l+1] = incl(l)
    int l  = s >> 1;
    int iS = __shfl(incl, l, 64);
    int xS = __shfl(dd.x, l, 64);
    int yS = __shfl(dd.y, l, 64);
    int end   = (s & 1) ? iS : (iS - yS);
    int dS    = (s & 1) ? yS : xS;
    int start = end - dS;
    if (start > TT) start = TT;
    if (end   > TT) end   = TT;
    int K = (end - start) * FF;   // rows of 256 floats; our slice = 4 float4 of each

    // lane covers float4 #fi of row r16: 4 lanes per 64B row-slice, 16 rows/round
    int r16 = lane >> 2;
    int fi  = lane & 3;
    const float4* base = (const float4*)e
        + (size_t)(b * TT + start) * (FF * CC / 4)
        + ce * 4 + fi;

    float4 acc = make_float4(0.f, 0.f, 0.f, 0.f);
    int k = r16;
    for (; k + 48 < K; k += 64) {     // 4 independent loads in flight
        float4 v0 = base[(size_t)(k     ) * 64];
        float4 v1 = base[(size_t)(k + 16) * 64];
        float4 v2 = base[(size_t)(k + 32) * 64];
        float4 v3 = base[(size_t)(k + 48) * 64];
        acc.x += v0.x + v1.x + v2.x + v3.x;
        acc.y += v0.y + v1.y + v2.y + v3.y;
        acc.z += v0.z + v1.z + v2.z + v3.z;
        acc.w += v0.w + v1.w + v2.w + v3.w;
    }
    for (; k < K; k += 16) {
        float4 v = base[(size_t)k * 64];
        acc.x += v.x; acc.y += v.y; acc.z += v.z; acc.w += v.w;
    }

    // reduce across the 16 row-groups (lanes sharing fi): xor over bits 2..5
    #pragma unroll
    for (int m = 4; m < 64; m <<= 1) {
        acc.x += __shfl_xor(acc.x, m, 64);
        acc.y += __shfl_xor(acc.y, m, 64);
        acc.z += __shfl_xor(acc.z, m, 64);
        acc.w += __shfl_xor(acc.w, m, 64);
    }

    if (lane < 4) {
        float inv = (dS > 0) ? 1.0f / (float)(dS * FF) : 0.0f;
        float4 r = make_float4(acc.x * inv, acc.y * inv, acc.z * inv, acc.w * inv);
        ((float4*)out)[(size_t)(b * SS + s) * 64 + ce * 4 + lane] = r;
    }
}

extern "C" void kernel_launch(void* const* d_in, const int* in_sizes, int n_in,
                              void* d_out, int out_size, void* d_ws, size_t ws_size,
                              hipStream_t stream) {
    const float* e   = (const float*)d_in[0];
    const int*   d   = (const int*)d_in[1];
    float*       out = (float*)d_out;

    fused_kernel<<<dim3(SS * 16 / 2, BH), 128, 0, stream>>>(e, d, out);
}

// Round 5
// 174.765 us; speedup vs baseline: 1.0144x; 1.0144x over previous
//
#include <hip/hip_runtime.h>

#define TT 1024
#define SS 128
#define FF 8
#define CC 256
#define BH 8

// One dispatch, 8192 one-wave workgroups: block (x, b) owns segment s = x & 127
// and channel-slice ce = x >> 7 (32 floats = one 128B line per row). Exact writer
// per output slice -> no atomics, no zero pass, no barriers, no LDS.
// s = x&127 (not x>>3) decorrelates consecutive blocks' segment lengths so each
// CU's resident task set averages ~16-32 iid lengths instead of 2-4 (the round-3
// mapping gave every CU 8 consecutive slices of the SAME segment).
__global__ __launch_bounds__(64) void fused_kernel(const float* __restrict__ e,
                                                   const int* __restrict__ dsrc,
                                                   float* __restrict__ out) {
    int x    = blockIdx.x;
    int b    = blockIdx.y;
    int lane = threadIdx.x;
    int s    = x & (SS - 1);
    int ce   = x >> 7;

    // ---- wave-redundant inclusive scan of d[b, :] (128 ints, 2 per lane) ----
    int2 dd = ((const int2*)(dsrc + b * SS))[lane];
    int incl = dd.x + dd.y;
    #pragma unroll
    for (int off = 1; off < 64; off <<= 1) {
        int n = __shfl_up(incl, off, 64);
        if (lane >= off) incl += n;
    }
    // cum[2l] = incl(l) - dd.y(l); cum[2l+1] = incl(l)
    int l  = s >> 1;
    int iS = __shfl(incl, l, 64);
    int xS = __shfl(dd.x, l, 64);
    int yS = __shfl(dd.y, l, 64);
    int end   = (s & 1) ? iS : (iS - yS);
    int dS    = (s & 1) ? yS : xS;
    int start = end - dS;
    if (start > TT) start = TT;
    if (end   > TT) end   = TT;
    int K = (end - start) * FF;       // rows of 256 floats; our slice = 8 float4 of each

    // lane covers float4 #fi of row k (k = r8 mod 8): 8 lanes per 128B row-line, 8 rows/round
    int r8 = lane >> 3;
    int fi = lane & 7;
    const float4* base = (const float4*)e
        + (size_t)(b * TT + start) * (FF * CC / 4)
        + ce * 8 + fi;

    float4 acc = make_float4(0.f, 0.f, 0.f, 0.f);
    int k = r8;
    for (; k + 24 < K; k += 32) {     // 4 independent loads in flight
        float4 v0 = base[(size_t)(k     ) * 64];
        float4 v1 = base[(size_t)(k +  8) * 64];
        float4 v2 = base[(size_t)(k + 16) * 64];
        float4 v3 = base[(size_t)(k + 24) * 64];
        acc.x += v0.x + v1.x + v2.x + v3.x;
        acc.y += v0.y + v1.y + v2.y + v3.y;
        acc.z += v0.z + v1.z + v2.z + v3.z;
        acc.w += v0.w + v1.w + v2.w + v3.w;
    }
    for (; k < K; k += 8) {
        float4 v = base[(size_t)k * 64];
        acc.x += v.x; acc.y += v.y; acc.z += v.z; acc.w += v.w;
    }

    // reduce across r8 groups (lanes sharing lane&7): xor over bits 3,4,5
    #pragma unroll
    for (int m = 8; m < 64; m <<= 1) {
        acc.x += __shfl_xor(acc.x, m, 64);
        acc.y += __shfl_xor(acc.y, m, 64);
        acc.z += __shfl_xor(acc.z, m, 64);
        acc.w += __shfl_xor(acc.w, m, 64);
    }

    if (lane < 8) {
        float inv = (dS > 0) ? 1.0f / (float)(dS * FF) : 0.0f;
        float4 r = make_float4(acc.x * inv, acc.y * inv, acc.z * inv, acc.w * inv);
        ((float4*)out)[(size_t)(b * SS + s) * 64 + ce * 8 + lane] = r;
    }
}

extern "C" void kernel_launch(void* const* d_in, const int* in_sizes, int n_in,
                              void* d_out, int out_size, void* d_ws, size_t ws_size,
                              hipStream_t stream) {
    const float* e   = (const float*)d_in[0];
    const int*   d   = (const int*)d_in[1];
    float*       out = (float*)d_out;

    fused_kernel<<<dim3(SS * 8, BH), 64, 0, stream>>>(e, d, out);
}